// Round 5
// baseline (1200.760 us; speedup 1.0000x reference)
//
#include <hip/hip_runtime.h>
#include <math.h>

// out = softmax(s @ X[:-1]^T) @ X[1:]
//   X: (8192,1024) fp32, s: (8191,1024) fp32, out: (8191,1024) fp32
// R7: BQ=64, KSPLIT=2, BK=256, 8 waves x (32 keys QK / 128-wide D PV).
//  - K and V streamed via global_load_lds into wave-private LDS rings
//    (K: 3 slots x 2KB/wave, V: 2 slots x 4KB/wave), counted vmcnt, no
//    extra barriers (wave-private staging), ~14KB in flight per wave.
//  - Q evicted from LDS: streamed per-iter from fragment-ordered Qg;
//    all 8 waves read identical addresses -> L1 dedup.
//  - softmax rescale scalar-ized per row (register pressure).

#define NQ 8191
#define NK 8191
#define DD 1024
#define BQ 64
#define BK 256
#define KSPLIT 2
#define KHALF 4096
#define ITERS 16
#define NW 8
#define NT 512

typedef _Float16 half8 __attribute__((ext_vector_type(8)));
typedef float float4v __attribute__((ext_vector_type(4)));

// ---------------- prep kernels: fragment-ordered K / V / Q ----------------

// Kf[g=key/16][kk=d/32][lane][8]: lane l holds K[g*16+(l&15)][kk*32+(l>>4)*8+e]
__global__ void prep_kf(const float* __restrict__ X, _Float16* __restrict__ Kf) {
    int b = blockIdx.x * 256 + threadIdx.x;
    int l  = b & 63;
    int kk = (b >> 6) & 31;
    int g  = b >> 11;
    int row = g * 16 + (l & 15);
    int col = kk * 32 + ((l >> 4) << 3);
    const float4v* src = (const float4v*)&X[(size_t)row * DD + col];
    float4v v0 = src[0], v1 = src[1];
    half8 h;
    h[0]=(_Float16)v0[0]; h[1]=(_Float16)v0[1]; h[2]=(_Float16)v0[2]; h[3]=(_Float16)v0[3];
    h[4]=(_Float16)v1[0]; h[5]=(_Float16)v1[1]; h[6]=(_Float16)v1[2]; h[7]=(_Float16)v1[3];
    *(half8*)&Kf[(size_t)b * 8] = h;
}

// Vf[h=d/16][kkg=key/32][lane][8]: lane l holds V^T[h*16+(l&15)][kkg*32+(l>>4)*8+e]
__global__ void prep_vf(const float* __restrict__ X, _Float16* __restrict__ Vf) {
    int b = blockIdx.x * 256 + threadIdx.x;
    int l   = b & 63;
    int kkg = (b >> 6) & 255;
    int h   = b >> 14;
    int d    = h * 16 + (l & 15);
    int key0 = kkg * 32 + ((l >> 4) << 3);
    half8 hv;
    #pragma unroll
    for (int e = 0; e < 8; ++e) {
        int row = key0 + e + 1;
        float v = (row < 8192) ? X[(size_t)row * DD + d] : 0.f;
        hv[e] = (_Float16)v;
    }
    *(half8*)&Vf[(size_t)b * 8] = hv;
}

// Qg[qt][qf][kk][lane][8]: lane l holds s[qt*64+qf*16+(l&15)][kk*32+(l>>4)*8+e]
__global__ void prep_qf(const float* __restrict__ s, _Float16* __restrict__ Qg) {
    int b = blockIdx.x * 256 + threadIdx.x;   // 1,048,576
    int l  = b & 63;
    int kk = (b >> 6) & 31;
    int qf = (b >> 11) & 3;
    int qt = b >> 13;
    int row = qt * 64 + qf * 16 + (l & 15);
    int col = kk * 32 + ((l >> 4) << 3);
    half8 hv;
    if (row < NQ) {
        const float4v* src = (const float4v*)&s[(size_t)row * DD + col];
        float4v v0 = src[0], v1 = src[1];
        hv[0]=(_Float16)v0[0]; hv[1]=(_Float16)v0[1]; hv[2]=(_Float16)v0[2]; hv[3]=(_Float16)v0[3];
        hv[4]=(_Float16)v1[0]; hv[5]=(_Float16)v1[1]; hv[6]=(_Float16)v1[2]; hv[7]=(_Float16)v1[3];
    } else {
        #pragma unroll
        for (int j = 0; j < 8; ++j) hv[j] = (_Float16)0.f;
    }
    *(half8*)&Qg[(size_t)b * 8] = hv;
}

// ---------------- flash kernel ----------------

__device__ __forceinline__ void gld16(const _Float16* g, _Float16* lp) {
    __builtin_amdgcn_global_load_lds(
        (const __attribute__((address_space(1))) unsigned int*)g,
        (__attribute__((address_space(3))) unsigned int*)lp, 16, 0, 0);
}

#define SBAR __builtin_amdgcn_sched_barrier(0)
#define WAITV(N) do { asm volatile("s_waitcnt vmcnt(" #N ")" ::: "memory"); \
                      __builtin_amdgcn_sched_barrier(0); } while (0)

// stage K fragments (2 groups) for kk into ring array ARR
#define IK(ARR, GB, kkv) do { \
    gld16(Kf + ((((size_t)(GB)    ) * 32 + (kkv)) << 9) + (l << 3), &ARR[w][0][0]); \
    gld16(Kf + ((((size_t)(GB) + 1) * 32 + (kkv)) << 9) + (l << 3), &ARR[w][1][0]); \
} while (0)

// load Q fragments (4 qf) for kk into register buffer QB
#define IQ(QB, kkv) do { \
    _Pragma("unroll") \
    for (int qf_ = 0; qf_ < 4; ++qf_) \
        QB[qf_] = *(const half8*)(Qg + (((size_t)(qtb4 + qf_) * 32 + (kkv)) << 9) + (l << 3)); \
} while (0)

// stage V half-slice hp (kk2=hp>>1, 4 dt frags) into ring array ARR
#define IV(ARR, hp) do { \
    _Pragma("unroll") \
    for (int j_ = 0; j_ < 4; ++j_) \
        gld16(Vf + (((size_t)(w * 8 + ((hp) & 1) * 4 + j_) * 256 + (kvb + ((hp) >> 1))) << 9) + (l << 3), \
              &ARR[w][j_][0]); \
} while (0)

// phase-1 step: consume K slot + Q buffer, 8 MFMAs
#define P1(kkc, ARR, QB, WAITM) do { \
    WAITM; \
    half8 k0_ = *(const half8*)&ARR[w][0][l << 3]; \
    half8 k1_ = *(const half8*)&ARR[w][1][l << 3]; \
    _Pragma("unroll") \
    for (int qf_ = 0; qf_ < 4; ++qf_) { \
        sa[qf_][0] = __builtin_amdgcn_mfma_f32_16x16x32_f16(QB[qf_], k0_, sa[qf_][0], 0, 0, 0); \
        sa[qf_][1] = __builtin_amdgcn_mfma_f32_16x16x32_f16(QB[qf_], k1_, sa[qf_][1], 0, 0, 0); \
    } \
} while (0)

// phase-3 step h: consume V slot (4 dt frags), 16 MFMAs; reload pa at even h
#define P3(hc, ARR, WAITM) do { \
    WAITM; \
    if (((hc) & 1) == 0) { \
        _Pragma("unroll") \
        for (int qf_ = 0; qf_ < 4; ++qf_) \
            pa[qf_] = *(const half8*)&Pf[(((qf_ * 8 + ((hc) >> 1)) * 64 + l) << 3)]; \
    } \
    _Pragma("unroll") \
    for (int j_ = 0; j_ < 4; ++j_) { \
        half8 vf_ = *(const half8*)&ARR[w][j_][l << 3]; \
        _Pragma("unroll") \
        for (int qf_ = 0; qf_ < 4; ++qf_) \
            o[qf_][((hc) & 1) * 4 + j_] = \
                __builtin_amdgcn_mfma_f32_16x16x32_f16(pa[qf_], vf_, o[qf_][((hc) & 1) * 4 + j_], 0, 0, 0); \
    } \
} while (0)

__launch_bounds__(NT, 2)
__global__ void flash(const _Float16* __restrict__ Qg,
                      const _Float16* __restrict__ Kf,
                      const _Float16* __restrict__ Vf,
                      _Float16* __restrict__ Op,
                      float2* __restrict__ ml) {
    // wave-private staging rings (separate arrays -> backend alias analysis)
    __shared__ _Float16 KSA[NW][2][512];   // 16 KB each
    __shared__ _Float16 KSB[NW][2][512];
    __shared__ _Float16 KSC[NW][2][512];
    __shared__ _Float16 VSA[NW][4][512];   // 32 KB each
    __shared__ _Float16 VSB[NW][4][512];
    __shared__ _Float16 Pf[16384];         // 32 KB fragment-linear P
    __shared__ float    Rm[BQ * NW];       // [row][wave], 2 KB

    const int t  = threadIdx.x;
    const int w  = t >> 6;
    const int l  = t & 63;
    const int ln = l & 15;
    const int q4 = l >> 4;

    const int bid = blockIdx.x;
    const int qt  = bid >> 1;
    const int ks  = bid & 1;
    const int q0  = qt * BQ;
    const int qtb4 = qt * 4;

    float4v o[4][8];
    #pragma unroll
    for (int qf = 0; qf < 4; ++qf)
        #pragma unroll
        for (int dt = 0; dt < 8; ++dt)
            o[qf][dt] = (float4v){0.f, 0.f, 0.f, 0.f};

    float m_run[16], l_run[16];
    #pragma unroll
    for (int i = 0; i < 16; ++i) { m_run[i] = -INFINITY; l_run[i] = 0.f; }

    const int pbase = w * 512 + q4 * 32 + ((ln >> 3) << 7) + (ln & 7);

    half8 qa[4], qb[4], pa[4];

    // prologue: K0..K2 slots + Q0,Q1 regs for it=0; drain with a barrier
    {
        const int gk0 = ks * 256 + w * 2;
        IK(KSA, gk0, 0);
        IK(KSB, gk0, 1);
        IK(KSC, gk0, 2);
        IQ(qa, 0);
        IQ(qb, 1);
    }
    __syncthreads();

    for (int it = 0; it < ITERS; ++it) {
        const int gk0  = ks * 256 + it * 16 + w * 2;
        const int itn  = (it + 1) & (ITERS - 1);
        const int gk0n = ks * 256 + itn * 16 + w * 2;
        const int kvb  = ks * 128 + it * 8;

        // ---- phase 1: S[64 q][wave's 32 keys], 32 pipelined kk steps ----
        float4v sa[4][2];
        #pragma unroll
        for (int qf = 0; qf < 4; ++qf) {
            sa[qf][0] = (float4v){0.f, 0.f, 0.f, 0.f};
            sa[qf][1] = (float4v){0.f, 0.f, 0.f, 0.f};
        }

        P1(0,  KSA, qa, SBAR);    IK(KSA, gk0, 3);  IQ(qa, 2);
        P1(1,  KSB, qb, SBAR);    IK(KSB, gk0, 4);  IQ(qb, 3);
        P1(2,  KSC, qa, WAITV(6)); IK(KSC, gk0, 5);  IQ(qa, 4);
        P1(3,  KSA, qb, WAITV(6)); IK(KSA, gk0, 6);  IQ(qb, 5);
        P1(4,  KSB, qa, WAITV(6)); IK(KSB, gk0, 7);  IQ(qa, 6);
        P1(5,  KSC, qb, WAITV(6)); IK(KSC, gk0, 8);  IQ(qb, 7);
        P1(6,  KSA, qa, WAITV(6)); IK(KSA, gk0, 9);  IQ(qa, 8);
        P1(7,  KSB, qb, WAITV(6)); IK(KSB, gk0, 10); IQ(qb, 9);
        P1(8,  KSC, qa, WAITV(6)); IK(KSC, gk0, 11); IQ(qa, 10);
        P1(9,  KSA, qb, WAITV(6)); IK(KSA, gk0, 12); IQ(qb, 11);
        P1(10, KSB, qa, WAITV(6)); IK(KSB, gk0, 13); IQ(qa, 12);
        P1(11, KSC, qb, WAITV(6)); IK(KSC, gk0, 14); IQ(qb, 13);
        P1(12, KSA, qa, WAITV(6)); IK(KSA, gk0, 15); IQ(qa, 14);
        P1(13, KSB, qb, WAITV(6)); IK(KSB, gk0, 16); IQ(qb, 15);
        P1(14, KSC, qa, WAITV(6)); IK(KSC, gk0, 17); IQ(qa, 16);
        P1(15, KSA, qb, WAITV(6)); IK(KSA, gk0, 18); IQ(qb, 17);
        P1(16, KSB, qa, WAITV(6)); IK(KSB, gk0, 19); IQ(qa, 18);
        P1(17, KSC, qb, WAITV(6)); IK(KSC, gk0, 20); IQ(qb, 19);
        P1(18, KSA, qa, WAITV(6)); IK(KSA, gk0, 21); IQ(qa, 20);
        P1(19, KSB, qb, WAITV(6)); IK(KSB, gk0, 22); IQ(qb, 21);
        P1(20, KSC, qa, WAITV(6)); IK(KSC, gk0, 23); IQ(qa, 22);
        P1(21, KSA, qb, WAITV(6)); IK(KSA, gk0, 24); IQ(qb, 23);
        P1(22, KSB, qa, WAITV(6)); IK(KSB, gk0, 25); IQ(qa, 24);
        P1(23, KSC, qb, WAITV(6)); IK(KSC, gk0, 26); IQ(qb, 25);
        P1(24, KSA, qa, WAITV(6)); IK(KSA, gk0, 27); IQ(qa, 26);
        P1(25, KSB, qb, WAITV(6)); IK(KSB, gk0, 28); IQ(qb, 27);
        P1(26, KSC, qa, WAITV(6)); IK(KSC, gk0, 29); IQ(qa, 28);
        P1(27, KSA, qb, WAITV(6)); IK(KSA, gk0, 30); IQ(qb, 29);
        P1(28, KSB, qa, WAITV(6)); IK(KSB, gk0, 31); IQ(qa, 30);
        P1(29, KSC, qb, WAITV(6)); IQ(qb, 31);
        P1(30, KSA, qa, WAITV(4)); IV(VSA, 0);
        P1(31, KSB, qb, WAITV(4)); IV(VSB, 1);

        const int kbase = ks * KHALF + it * BK + w * 32;
        const bool bad0 = (kbase + ln) >= NK;
        const bool bad1 = (kbase + 16 + ln) >= NK;

        // ---- wave-local row max, per-row scalar (low reg pressure) ----
        #pragma unroll
        for (int qf = 0; qf < 4; ++qf)
            #pragma unroll
            for (int r = 0; r < 4; ++r) {
                float v0 = bad0 ? -INFINITY : sa[qf][0][r];
                float v1 = bad1 ? -INFINITY : sa[qf][1][r];
                float v = fmaxf(v0, v1);
                v = fmaxf(v, __shfl_xor(v, 1, 64));
                v = fmaxf(v, __shfl_xor(v, 2, 64));
                v = fmaxf(v, __shfl_xor(v, 4, 64));
                v = fmaxf(v, __shfl_xor(v, 8, 64));
                if (ln == 0) Rm[(qf * 16 + q4 * 4 + r) * NW + w] = v;
            }
        __syncthreads();   // B: Rm visible (drains V0/V1 prefetch - ready early)

        // ---- per row: global max, alpha, rescale O/l, exp, P write ----
        #pragma unroll
        for (int qf = 0; qf < 4; ++qf)
            #pragma unroll
            for (int r = 0; r < 4; ++r) {
                const int i = qf * 4 + r;
                const int row = qf * 16 + q4 * 4 + r;
                float4v ra = *(const float4v*)&Rm[row * NW];
                float4v rb = *(const float4v*)&Rm[row * NW + 4];
                float mn = fmaxf(fmaxf(fmaxf(ra[0], ra[1]), fmaxf(ra[2], ra[3])),
                                 fmaxf(fmaxf(rb[0], rb[1]), fmaxf(rb[2], rb[3])));
                mn = fmaxf(mn, m_run[i]);
                float al = __expf(m_run[i] - mn);
                m_run[i] = mn;
                float p0 = bad0 ? 0.f : __expf(sa[qf][0][r] - mn);
                float p1 = bad1 ? 0.f : __expf(sa[qf][1][r] - mn);
                l_run[i] = l_run[i] * al + p0 + p1;
                Pf[pbase + qf * 4096 + r * 8]       = (_Float16)p0;
                Pf[pbase + qf * 4096 + r * 8 + 256] = (_Float16)p1;
                #pragma unroll
                for (int dt = 0; dt < 8; ++dt) o[qf][dt][r] *= al;
            }
        __syncthreads();   // D: Pf ready

        // ---- phase 3: O += P.V, 16 pipelined half-slices ----
        P3(0,  VSA, SBAR);      IV(VSA, 2);
        P3(1,  VSB, SBAR);      IV(VSB, 3);
        P3(2,  VSA, WAITV(4));  IV(VSA, 4);
        P3(3,  VSB, WAITV(4));  IV(VSB, 5);
        P3(4,  VSA, WAITV(4));  IV(VSA, 6);
        P3(5,  VSB, WAITV(4));  IV(VSB, 7);
        P3(6,  VSA, WAITV(4));  IV(VSA, 8);
        P3(7,  VSB, WAITV(4));  IV(VSB, 9);
        P3(8,  VSA, WAITV(4));  IV(VSA, 10);
        P3(9,  VSB, WAITV(4));  IV(VSB, 11);
        P3(10, VSA, WAITV(4));  IV(VSA, 12);
        P3(11, VSB, WAITV(4));  IV(VSB, 13);
        P3(12, VSA, WAITV(4));  IV(VSA, 14);
        P3(13, VSB, WAITV(4));  IV(VSB, 15); IK(KSA, gk0n, 0); IK(KSB, gk0n, 1);
        P3(14, VSA, WAITV(8));  IK(KSC, gk0n, 2); IQ(qa, 0);
        P3(15, VSB, WAITV(10)); IQ(qb, 1);

        __syncthreads();   // A: Pf/Rm free; drains next-iter prologue
    }

    // ---- epilogue: reduce l across lanes and waves, store partials ----
    #pragma unroll
    for (int qf = 0; qf < 4; ++qf)
        #pragma unroll
        for (int r = 0; r < 4; ++r) {
            float v = l_run[qf * 4 + r];
            v += __shfl_xor(v, 1, 64);
            v += __shfl_xor(v, 2, 64);
            v += __shfl_xor(v, 4, 64);
            v += __shfl_xor(v, 8, 64);
            if (ln == 0) Rm[(qf * 16 + q4 * 4 + r) * NW + w] = v;
        }
    __syncthreads();

    float lsum[16], inv[16];
    #pragma unroll
    for (int qf = 0; qf < 4; ++qf)
        #pragma unroll
        for (int r = 0; r < 4; ++r) {
            int row = qf * 16 + q4 * 4 + r;
            float4v ra = *(const float4v*)&Rm[row * NW];
            float4v rb = *(const float4v*)&Rm[row * NW + 4];
            float sum = (ra[0] + ra[1] + ra[2] + ra[3])
                      + (rb[0] + rb[1] + rb[2] + rb[3]);
            lsum[qf * 4 + r] = sum;
            inv[qf * 4 + r] = 1.f / sum;
        }

    if (w == 0 && ln == 0) {
        #pragma unroll
        for (int qf = 0; qf < 4; ++qf)
            #pragma unroll
            for (int r = 0; r < 4; ++r) {
                int row = q0 + qf * 16 + q4 * 4 + r;
                if (row < NQ)
                    ml[ks * 8192 + row] = make_float2(m_run[qf * 4 + r], lsum[qf * 4 + r]);
            }
    }

    #pragma unroll
    for (int qf = 0; qf < 4; ++qf)
        #pragma unroll
        for (int dt = 0; dt < 8; ++dt)
            #pragma unroll
            for (int r = 0; r < 4; ++r) {
                int row = q0 + qf * 16 + q4 * 4 + r;
                int col = w * 128 + dt * 16 + ln;
                if (row < NQ)
                    Op[((size_t)ks * NQ + row) * DD + col] =
                        (_Float16)(o[qf][dt][r] * inv[qf * 4 + r]);
            }
}

// out = w0 * Op[0] + w1 * Op[1], weights from (m,l) pairs
__global__ void combine(const _Float16* __restrict__ Op,
                        const float2* __restrict__ ml,
                        float* __restrict__ out) {
    size_t idx = ((size_t)blockIdx.x * 256 + threadIdx.x) * 8;
    if (idx >= (size_t)NQ * DD) return;
    int row = (int)(idx >> 10);
    float2 a = ml[row];
    float2 b = ml[8192 + row];
    float m  = fmaxf(a.x, b.x);
    float w0 = a.y * __expf(a.x - m);
    float w1 = b.y * __expf(b.x - m);
    float inv = 1.f / (w0 + w1);
    w0 *= inv; w1 *= inv;
    half8 h0 = *(const half8*)&Op[idx];
    half8 h1 = *(const half8*)&Op[(size_t)NQ * DD + idx];
    float4v o0, o1;
    #pragma unroll
    for (int e = 0; e < 4; ++e) o0[e] = w0 * (float)h0[e] + w1 * (float)h1[e];
    #pragma unroll
    for (int e = 0; e < 4; ++e) o1[e] = w0 * (float)h0[e + 4] + w1 * (float)h1[e + 4];
    *(float4v*)&out[idx]     = o0;
    *(float4v*)&out[idx + 4] = o1;
}

extern "C" void kernel_launch(void* const* d_in, const int* in_sizes, int n_in,
                              void* d_out, int out_size, void* d_ws, size_t ws_size,
                              hipStream_t stream) {
    const float* X = (const float*)d_in[0];
    const float* s = (const float*)d_in[1];
    float* out = (float*)d_out;

    _Float16* Kf = (_Float16*)d_ws;                  // 16 MiB
    _Float16* Vf = Kf + (size_t)8192 * 1024;         // 16 MiB
    _Float16* Qg = Vf + (size_t)8192 * 1024;         // 16 MiB
    _Float16* Op = Qg + (size_t)8192 * 1024;         // 32 MiB
    float2*   ml = (float2*)(Op + (size_t)2 * NQ * DD);  // 128 KiB

    prep_kf<<<4096, 256, 0, stream>>>(X, Kf);
    prep_vf<<<4096, 256, 0, stream>>>(X, Vf);
    prep_qf<<<4096, 256, 0, stream>>>(s, Qg);
    flash<<<KSPLIT * ((NQ + BQ - 1) / BQ), NT, 0, stream>>>(Qg, Kf, Vf, Op, ml);
    combine<<<4096, 256, 0, stream>>>(Op, ml, out);
}

// Round 6
// 683.134 us; speedup vs baseline: 1.7577x; 1.7577x over previous
//
#include <hip/hip_runtime.h>
#include <math.h>

// out = softmax(s @ X[:-1]^T) @ X[1:]
//   X: (8192,1024) fp32, s: (8191,1024) fp32, out: (8191,1024) fp32
// R8 = R5 (best verified: 605us flash) + XCD-pure key-half mapping ONLY.
//   All 32 blocks on an XCD stream the same K/V half on the same iteration
//   schedule -> per-iter working set 1MB fits 4MB XCD L2 with 32-way
//   concurrent reuse. Per-CU streaming rate is MSHR-bound (~8KB in flight /
//   latency), so L2-hit latency (~200cy) instead of LLC (~700cy) is the lever.

#define NQ 8191
#define NK 8191
#define DD 1024
#define BQ 64
#define BK 256
#define KSPLIT 2
#define KHALF 4096
#define ITERS 16
#define NW 8
#define NT 512
#define QKK 31         // Q k-groups in LDS; group 31 lives in registers

typedef _Float16 half8 __attribute__((ext_vector_type(8)));
typedef float float4v __attribute__((ext_vector_type(4)));

// Kf[g=key/16][kk=d/32][lane][8]: lane l holds K[g*16+(l&15)][kk*32+(l>>4)*8+e]
__global__ void prep_kf(const float* __restrict__ X, _Float16* __restrict__ Kf) {
    int b = blockIdx.x * 256 + threadIdx.x;
    int l  = b & 63;
    int kk = (b >> 6) & 31;
    int g  = b >> 11;
    int row = g * 16 + (l & 15);
    int col = kk * 32 + ((l >> 4) << 3);
    const float4v* src = (const float4v*)&X[(size_t)row * DD + col];
    float4v v0 = src[0], v1 = src[1];
    half8 h;
    h[0]=(_Float16)v0[0]; h[1]=(_Float16)v0[1]; h[2]=(_Float16)v0[2]; h[3]=(_Float16)v0[3];
    h[4]=(_Float16)v1[0]; h[5]=(_Float16)v1[1]; h[6]=(_Float16)v1[2]; h[7]=(_Float16)v1[3];
    *(half8*)&Kf[(size_t)b * 8] = h;
}

// Vf[h=d/16][kkg=key/32][lane][8]: lane l holds V^T[h*16+(l&15)][kkg*32+(l>>4)*8+e]
__global__ void prep_vf(const float* __restrict__ X, _Float16* __restrict__ Vf) {
    int b = blockIdx.x * 256 + threadIdx.x;
    int l   = b & 63;
    int kkg = (b >> 6) & 255;
    int h   = b >> 14;
    int d    = h * 16 + (l & 15);
    int key0 = kkg * 32 + ((l >> 4) << 3);
    half8 hv;
    #pragma unroll
    for (int e = 0; e < 8; ++e) {
        int row = key0 + e + 1;
        float v = (row < 8192) ? X[(size_t)row * DD + d] : 0.f;
        hv[e] = (_Float16)v;
    }
    *(half8*)&Vf[(size_t)b * 8] = hv;
}

__launch_bounds__(NT, 2)
__global__ void flash(const float* __restrict__ s,
                      const _Float16* __restrict__ Kf,
                      const _Float16* __restrict__ Vf,
                      _Float16* __restrict__ Op,
                      float2* __restrict__ ml) {
    __shared__ _Float16 Qf[4 * QKK * 64 * 8];   // 126,976 B, fragment-linear
    __shared__ _Float16 Pf[4 * 8 * 64 * 8];     // 32,768 B, fragment-linear
    __shared__ float    Rm[NW * BQ];            // 2 KB (reused as Rl in epilogue)

    const int t  = threadIdx.x;
    const int w  = t >> 6;       // wave 0..7
    const int l  = t & 63;
    const int ln = l & 15;
    const int q4 = l >> 4;

    // XCD-pure mapping (the ONLY change vs R5): blocks dispatch round-robin
    // across XCDs (xcd = bid % 8); give every block on an XCD the same key
    // half so the per-iteration 1MB K/V window is L2-resident with 32-way
    // concurrent reuse. qt spread so each XCD pair covers all q-tiles.
    const int bid  = blockIdx.x;
    const int xcd  = bid & 7;
    const int slot = bid >> 3;
    const int ks   = xcd & 1;
    const int qt   = slot * 4 + (xcd >> 1);
    const int q0   = qt * BQ;

    // ---- stage Q: fragment-linear LDS (groups 0..30), group 31 in regs ----
    for (int e = t; e < 4 * QKK * 64; e += NT) {
        int ll  = e & 63;
        int rem = e >> 6;
        int kk  = rem % QKK;
        int qf  = rem / QKK;
        int row = qf * 16 + (ll & 15);
        int col = kk * 32 + ((ll >> 4) << 3);
        half8 hv;
        if (q0 + row < NQ) {
            const float4v* src = (const float4v*)&s[(size_t)(q0 + row) * DD + col];
            float4v v0 = src[0], v1 = src[1];
            hv[0]=(_Float16)v0[0]; hv[1]=(_Float16)v0[1]; hv[2]=(_Float16)v0[2]; hv[3]=(_Float16)v0[3];
            hv[4]=(_Float16)v1[0]; hv[5]=(_Float16)v1[1]; hv[6]=(_Float16)v1[2]; hv[7]=(_Float16)v1[3];
        } else {
            #pragma unroll
            for (int j = 0; j < 8; ++j) hv[j] = (_Float16)0.f;
        }
        *(half8*)&Qf[(size_t)e * 8] = hv;
    }
    half8 qreg[4];
    #pragma unroll
    for (int qf = 0; qf < 4; ++qf) {
        int row = qf * 16 + ln;
        int col = QKK * 32 + (q4 << 3);
        half8 hv;
        if (q0 + row < NQ) {
            const float4v* src = (const float4v*)&s[(size_t)(q0 + row) * DD + col];
            float4v v0 = src[0], v1 = src[1];
            hv[0]=(_Float16)v0[0]; hv[1]=(_Float16)v0[1]; hv[2]=(_Float16)v0[2]; hv[3]=(_Float16)v0[3];
            hv[4]=(_Float16)v1[0]; hv[5]=(_Float16)v1[1]; hv[6]=(_Float16)v1[2]; hv[7]=(_Float16)v1[3];
        } else {
            #pragma unroll
            for (int j = 0; j < 8; ++j) hv[j] = (_Float16)0.f;
        }
        qreg[qf] = hv;
    }
    __syncthreads();

    // O accumulator: wave w owns D chunk [w*128, w*128+128): 4 qf x 8 dt
    float4v o[4][8];
    #pragma unroll
    for (int qf = 0; qf < 4; ++qf)
        #pragma unroll
        for (int dt = 0; dt < 8; ++dt)
            o[qf][dt] = (float4v){0.f, 0.f, 0.f, 0.f};

    float m_run[16], l_run[16];
    #pragma unroll
    for (int i = 0; i < 16; ++i) { m_run[i] = -INFINITY; l_run[i] = 0.f; }

    const int pbase = w * 512 + q4 * 32 + ((ln >> 3) << 7) + (ln & 7);

    for (int it = 0; it < ITERS; ++it) {
        // ---- phase 1: S[64 q][this wave's 32 keys], full-D contraction ----
        const _Float16* kp0 = Kf + (size_t)(ks * 256 + it * 16 + w * 2) * 16384 + (size_t)l * 8;
        float4v sa[4][2];
        #pragma unroll
        for (int qf = 0; qf < 4; ++qf) {
            sa[qf][0] = (float4v){0.f, 0.f, 0.f, 0.f};
            sa[qf][1] = (float4v){0.f, 0.f, 0.f, 0.f};
        }
        #pragma unroll 4
        for (int kk = 0; kk < QKK; ++kk) {
            half8 k0 = *(const half8*)(kp0 + kk * 512);
            half8 k1 = *(const half8*)(kp0 + 16384 + kk * 512);
            #pragma unroll
            for (int qf = 0; qf < 4; ++qf) {
                half8 qa = *(const half8*)&Qf[((qf * QKK + kk) * 64 + l) * 8];
                sa[qf][0] = __builtin_amdgcn_mfma_f32_16x16x32_f16(qa, k0, sa[qf][0], 0, 0, 0);
                sa[qf][1] = __builtin_amdgcn_mfma_f32_16x16x32_f16(qa, k1, sa[qf][1], 0, 0, 0);
            }
        }
        {   // k-group 31 from registers
            half8 k0 = *(const half8*)(kp0 + 31 * 512);
            half8 k1 = *(const half8*)(kp0 + 16384 + 31 * 512);
            #pragma unroll
            for (int qf = 0; qf < 4; ++qf) {
                sa[qf][0] = __builtin_amdgcn_mfma_f32_16x16x32_f16(qreg[qf], k0, sa[qf][0], 0, 0, 0);
                sa[qf][1] = __builtin_amdgcn_mfma_f32_16x16x32_f16(qreg[qf], k1, sa[qf][1], 0, 0, 0);
            }
        }

        const int kbase = ks * KHALF + it * BK + w * 32;
        const bool bad0 = (kbase + ln) >= NK;
        const bool bad1 = (kbase + 16 + ln) >= NK;

        // ---- wave-local row max over this wave's 32 keys ----
        float pm[16];
        #pragma unroll
        for (int qf = 0; qf < 4; ++qf)
            #pragma unroll
            for (int r = 0; r < 4; ++r) {
                float v0 = bad0 ? -INFINITY : sa[qf][0][r];
                float v1 = bad1 ? -INFINITY : sa[qf][1][r];
                pm[qf * 4 + r] = fmaxf(v0, v1);
            }
        #pragma unroll
        for (int i = 0; i < 16; ++i) {
            float v = pm[i];
            v = fmaxf(v, __shfl_xor(v, 1, 64));
            v = fmaxf(v, __shfl_xor(v, 2, 64));
            v = fmaxf(v, __shfl_xor(v, 4, 64));
            v = fmaxf(v, __shfl_xor(v, 8, 64));
            pm[i] = v;
        }
        if (ln == 0) {
            #pragma unroll
            for (int qf = 0; qf < 4; ++qf)
                #pragma unroll
                for (int r = 0; r < 4; ++r)
                    Rm[w * BQ + qf * 16 + q4 * 4 + r] = pm[qf * 4 + r];
        }
        __syncthreads();   // B: Rm visible

        // ---- global row max, alpha, P, l ----
        float al[16];
        #pragma unroll
        for (int qf = 0; qf < 4; ++qf)
            #pragma unroll
            for (int r = 0; r < 4; ++r) {
                int row = qf * 16 + q4 * 4 + r;
                int i = qf * 4 + r;
                float v = m_run[i];
                #pragma unroll
                for (int wv = 0; wv < NW; ++wv) v = fmaxf(v, Rm[wv * BQ + row]);
                al[i] = __expf(m_run[i] - v);
                m_run[i] = v;
            }
        #pragma unroll
        for (int i = 0; i < 16; ++i) l_run[i] *= al[i];
        #pragma unroll
        for (int qf = 0; qf < 4; ++qf)
            #pragma unroll
            for (int r = 0; r < 4; ++r) {
                int i = qf * 4 + r;
                float p0 = bad0 ? 0.f : __expf(sa[qf][0][r] - m_run[i]);
                float p1 = bad1 ? 0.f : __expf(sa[qf][1][r] - m_run[i]);
                l_run[i] += p0 + p1;
                Pf[pbase + qf * 4096 + r * 8]       = (_Float16)p0;
                Pf[pbase + qf * 4096 + r * 8 + 256] = (_Float16)p1;
            }
        // rescale O
        #pragma unroll
        for (int qf = 0; qf < 4; ++qf)
            #pragma unroll
            for (int dt = 0; dt < 8; ++dt)
                #pragma unroll
                for (int r = 0; r < 4; ++r)
                    o[qf][dt][r] *= al[qf * 4 + r];
        __syncthreads();   // D: Pf ready

        // ---- phase 3: O += P . V over all 256 keys, wave's 128-wide D ----
        const _Float16* vp = Vf + (size_t)(w * 8) * 131072
                             + (size_t)(ks * 128 + it * 8) * 512 + (size_t)l * 8;
        #pragma unroll 2
        for (int kk2 = 0; kk2 < 8; ++kk2) {
            half8 pa[4];
            #pragma unroll
            for (int qf = 0; qf < 4; ++qf)
                pa[qf] = *(const half8*)&Pf[((qf * 8 + kk2) * 64 + l) * 8];
            #pragma unroll
            for (int dt = 0; dt < 8; ++dt) {
                half8 vf = *(const half8*)(vp + (size_t)dt * 131072 + kk2 * 512);
                #pragma unroll
                for (int qf = 0; qf < 4; ++qf)
                    o[qf][dt] = __builtin_amdgcn_mfma_f32_16x16x32_f16(pa[qf], vf, o[qf][dt], 0, 0, 0);
            }
        }
        __syncthreads();   // A: Pf/Rm free for next iter
    }

    // ---- epilogue: reduce l across lanes and waves, store partials ----
    float lt[16];
    #pragma unroll
    for (int i = 0; i < 16; ++i) {
        float v = l_run[i];
        v += __shfl_xor(v, 1, 64);
        v += __shfl_xor(v, 2, 64);
        v += __shfl_xor(v, 4, 64);
        v += __shfl_xor(v, 8, 64);
        lt[i] = v;
    }
    if (ln == 0) {
        #pragma unroll
        for (int qf = 0; qf < 4; ++qf)
            #pragma unroll
            for (int r = 0; r < 4; ++r)
                Rm[w * BQ + qf * 16 + q4 * 4 + r] = lt[qf * 4 + r];
    }
    __syncthreads();

    float lsum[16], inv[16];
    #pragma unroll
    for (int qf = 0; qf < 4; ++qf)
        #pragma unroll
        for (int r = 0; r < 4; ++r) {
            int row = qf * 16 + q4 * 4 + r;
            float sum = 0.f;
            #pragma unroll
            for (int wv = 0; wv < NW; ++wv) sum += Rm[wv * BQ + row];
            lsum[qf * 4 + r] = sum;
            inv[qf * 4 + r] = 1.f / sum;
        }

    if (w == 0 && ln == 0) {
        #pragma unroll
        for (int qf = 0; qf < 4; ++qf)
            #pragma unroll
            for (int r = 0; r < 4; ++r) {
                int row = q0 + qf * 16 + q4 * 4 + r;
                int i = qf * 4 + r;
                if (row < NQ)
                    ml[ks * 8192 + row] = make_float2(m_run[i], lsum[i]);
            }
    }

    #pragma unroll
    for (int qf = 0; qf < 4; ++qf)
        #pragma unroll
        for (int dt = 0; dt < 8; ++dt)
            #pragma unroll
            for (int r = 0; r < 4; ++r) {
                int row = q0 + qf * 16 + q4 * 4 + r;
                int col = w * 128 + dt * 16 + ln;
                if (row < NQ)
                    Op[((size_t)ks * NQ + row) * DD + col] =
                        (_Float16)(o[qf][dt][r] * inv[qf * 4 + r]);
            }
}

// out = w0 * Op[0] + w1 * Op[1], weights from (m,l) pairs
__global__ void combine(const _Float16* __restrict__ Op,
                        const float2* __restrict__ ml,
                        float* __restrict__ out) {
    size_t idx = ((size_t)blockIdx.x * 256 + threadIdx.x) * 8;
    if (idx >= (size_t)NQ * DD) return;
    int row = (int)(idx >> 10);
    float2 a = ml[row];
    float2 b = ml[8192 + row];
    float m  = fmaxf(a.x, b.x);
    float w0 = a.y * __expf(a.x - m);
    float w1 = b.y * __expf(b.x - m);
    float inv = 1.f / (w0 + w1);
    w0 *= inv; w1 *= inv;
    half8 h0 = *(const half8*)&Op[idx];
    half8 h1 = *(const half8*)&Op[(size_t)NQ * DD + idx];
    float4v o0, o1;
    #pragma unroll
    for (int e = 0; e < 4; ++e) o0[e] = w0 * (float)h0[e] + w1 * (float)h1[e];
    #pragma unroll
    for (int e = 0; e < 4; ++e) o1[e] = w0 * (float)h0[e + 4] + w1 * (float)h1[e + 4];
    *(float4v*)&out[idx]     = o0;
    *(float4v*)&out[idx + 4] = o1;
}

extern "C" void kernel_launch(void* const* d_in, const int* in_sizes, int n_in,
                              void* d_out, int out_size, void* d_ws, size_t ws_size,
                              hipStream_t stream) {
    const float* X = (const float*)d_in[0];
    const float* s = (const float*)d_in[1];
    float* out = (float*)d_out;

    _Float16* Kf = (_Float16*)d_ws;                  // 16 MiB
    _Float16* Vf = Kf + (size_t)8192 * 1024;         // 16 MiB
    _Float16* Op = Vf + (size_t)8192 * 1024;         // 32 MiB
    float2*   ml = (float2*)(Op + (size_t)2 * NQ * DD);  // 128 KiB

    prep_kf<<<4096, 256, 0, stream>>>(X, Kf);
    prep_vf<<<4096, 256, 0, stream>>>(X, Vf);
    flash<<<KSPLIT * ((NQ + BQ - 1) / BQ), NT, 0, stream>>>(s, Kf, Vf, Op, ml);
    combine<<<4096, 256, 0, stream>>>(Op, ml, out);
}